// Round 9
// baseline (584.155 us; speedup 1.0000x reference)
//
#include <hip/hip_runtime.h>
#include <stdint.h>

#define NB 4096
#define NS 512
#define NA 64
#define NH1 1024
#define NH2 512

typedef __attribute__((ext_vector_type(8))) short bf16x8;
typedef __attribute__((ext_vector_type(4))) float f32x4;

__device__ __forceinline__ unsigned short f2bf(float f) {
    union { float f; unsigned u; } v; v.f = f;
    return (unsigned short)((v.u + 0x8000u) >> 16);   // round-half-up bf16
}
__device__ __forceinline__ float bf2f(unsigned short h) {
    union { float f; unsigned u; } v; v.u = ((unsigned)h) << 16;
    return v.f;
}
__device__ __forceinline__ float bflo(unsigned u) {
    union { unsigned u; float f; } v; v.u = u << 16; return v.f;
}
__device__ __forceinline__ float bfhi(unsigned u) {
    union { unsigned u; float f; } v; v.u = u & 0xFFFF0000u; return v.f;
}
// truncating pack of two f32 -> bf16x2 (bias cancels in u/||u||): 1 v_perm
__device__ __forceinline__ unsigned packtrunc(float lo, float hi) {
    union { float f; unsigned u; } a, b; a.f = lo; b.f = hi;
    return __builtin_amdgcn_perm(b.u, a.u, 0x07060302u);
}
__device__ __forceinline__ void split2(float x, unsigned short& h, unsigned short& l) {
    unsigned short hh = f2bf(x);
    h = hh;
    l = f2bf(x - bf2f(hh));
}
__device__ __forceinline__ void async_copy16(const void* g, void* l) {
    __builtin_amdgcn_global_load_lds((const __attribute__((address_space(1))) void*)g,
                                     (__attribute__((address_space(3))) void*)l, 16, 0, 0);
}

// ---------------- P0: nb[b] = sqrt(||s_b||^2 + 1) + 1e-8 ----------------
__global__ void knorm(const float* __restrict__ S, float* __restrict__ nb) {
    int b = blockIdx.x; int l = threadIdx.x; // one wave
    const float* row = S + b * NS;
    float s = 0.f;
    for (int k = l; k < NS; k += 64) { float v = row[k]; s = fmaf(v, v, s); }
    for (int off = 32; off; off >>= 1) s += __shfl_down(s, off, 64);
    if (l == 0) nb[b] = sqrtf(s + 1.0f) + 1e-8f;
}

// ---------------- P1: W2f (frag-packed in exact read order, 8KB tiles) + caT2 ----------
// W2f short idx i = kc*16384 + cbb*4096 + f*512 + l*8 + j, f = wcc*4 + nt:
//   value = W2[cbb*128 + (f>>2)*64 + (f&3)*16 + (l&15)][kc*32 + (l>>4)*8 + j]
// (i.e. the B-fragment each lane reads -- no swizzle needed, DMA order == read order)
// caT2[at][kc][a_loc][kk] = W1[(kc*32+kk)*576 + 512 + at*16 + a_loc]
__global__ void kprep(const float* __restrict__ W1, const float* __restrict__ W2,
                      unsigned short* __restrict__ W2f, unsigned short* __restrict__ caT2) {
    int i = blockIdx.x * 256 + threadIdx.x;
    if (i < 524288) {
        int j = i & 7; int l = (i >> 3) & 63; int f = (i >> 9) & 7;
        int cbb = (i >> 12) & 3; int kc = i >> 14;
        int n = cbb * 128 + (f >> 2) * 64 + (f & 3) * 16 + (l & 15);
        int k = kc * 32 + (l >> 4) * 8 + j;
        W2f[i] = f2bf(W2[(size_t)n * NH1 + k]);
    } else {
        int j2 = i - 524288;                 // 65536 entries
        int kk = j2 & 31; int a_loc = (j2 >> 5) & 15;
        int kc = (j2 >> 9) & 31; int att = j2 >> 14;
        int o = kc * 32 + kk;
        caT2[j2] = f2bf(W1[(size_t)o * 576 + 512 + att * 16 + a_loc]);
    }
}

// ---------------- P2: Gt'[kc][b][32k] bf16 = s@W1s^T + b1*nb  (split-bf16, 3 GEMMs) ----
__global__ __launch_bounds__(256) void kgemm1(
        const float* __restrict__ Sm, const float* __restrict__ W1,
        const float* __restrict__ b1, const float* __restrict__ nb,
        unsigned short* __restrict__ Gt) {
    const int m0 = (blockIdx.x >> 3) * 128;
    const int n0 = (blockIdx.x & 7) * 128;
    __shared__ unsigned short Ah[128][40], Al[128][40], Bh[128][40], Bl[128][40];
    int t = threadIdx.x;
    int lane = t & 63, wave = t >> 6;
    int wr = wave >> 1, wc = wave & 1;
    int qd = lane >> 4, cl = lane & 15;
    int r = t >> 1, seg = t & 1;
    f32x4 acc[4][4] = {};

    for (int k0 = 0; k0 < 512; k0 += 32) {
        {
            const float4* as4 = (const float4*)(Sm + (size_t)(m0 + r) * NS + k0 + seg * 16);
            const float4* bs4 = (const float4*)(W1 + (size_t)(n0 + r) * 576 + k0 + seg * 16);
            unsigned* ah = (unsigned*)&Ah[r][seg * 16];
            unsigned* al = (unsigned*)&Al[r][seg * 16];
            unsigned* bh = (unsigned*)&Bh[r][seg * 16];
            unsigned* bl = (unsigned*)&Bl[r][seg * 16];
#pragma unroll
            for (int v = 0; v < 4; v++) {
                float4 fa = as4[v];
                unsigned short h0,h1,h2,h3,l0,l1,l2,l3;
                split2(fa.x,h0,l0); split2(fa.y,h1,l1); split2(fa.z,h2,l2); split2(fa.w,h3,l3);
                ah[v*2]   = (unsigned)h0 | ((unsigned)h1 << 16);
                ah[v*2+1] = (unsigned)h2 | ((unsigned)h3 << 16);
                al[v*2]   = (unsigned)l0 | ((unsigned)l1 << 16);
                al[v*2+1] = (unsigned)l2 | ((unsigned)l3 << 16);
                float4 fb = bs4[v];
                split2(fb.x,h0,l0); split2(fb.y,h1,l1); split2(fb.z,h2,l2); split2(fb.w,h3,l3);
                bh[v*2]   = (unsigned)h0 | ((unsigned)h1 << 16);
                bh[v*2+1] = (unsigned)h2 | ((unsigned)h3 << 16);
                bl[v*2]   = (unsigned)l0 | ((unsigned)l1 << 16);
                bl[v*2+1] = (unsigned)l2 | ((unsigned)l3 << 16);
            }
        }
        __syncthreads();
        bf16x8 a_h[4], a_l[4], b_h[4], b_l[4];
#pragma unroll
        for (int mt = 0; mt < 4; mt++) {
            a_h[mt] = *(const bf16x8*)&Ah[wr*64 + mt*16 + cl][qd*8];
            a_l[mt] = *(const bf16x8*)&Al[wr*64 + mt*16 + cl][qd*8];
        }
#pragma unroll
        for (int nt = 0; nt < 4; nt++) {
            b_h[nt] = *(const bf16x8*)&Bh[wc*64 + nt*16 + cl][qd*8];
            b_l[nt] = *(const bf16x8*)&Bl[wc*64 + nt*16 + cl][qd*8];
        }
#pragma unroll
        for (int mt = 0; mt < 4; mt++)
#pragma unroll
            for (int nt = 0; nt < 4; nt++) {
                acc[mt][nt] = __builtin_amdgcn_mfma_f32_16x16x32_bf16(a_h[mt], b_h[nt], acc[mt][nt], 0, 0, 0);
                acc[mt][nt] = __builtin_amdgcn_mfma_f32_16x16x32_bf16(a_h[mt], b_l[nt], acc[mt][nt], 0, 0, 0);
                acc[mt][nt] = __builtin_amdgcn_mfma_f32_16x16x32_bf16(a_l[mt], b_h[nt], acc[mt][nt], 0, 0, 0);
            }
        __syncthreads();
    }
#pragma unroll
    for (int mt = 0; mt < 4; mt++)
#pragma unroll
        for (int i = 0; i < 4; i++) {
            int m = m0 + wr*64 + mt*16 + qd*4 + i;
            float nbv = nb[m];
#pragma unroll
            for (int nt = 0; nt < 4; nt++) {
                int n = n0 + wc*64 + nt*16 + cl;
                float val = fmaf(b1[n], nbv, acc[mt][nt][i]);
                Gt[((size_t)(n >> 5) * NB + m) * 32 + (n & 31)] = f2bf(val);
            }
        }
}

// ---------------- Main: 256 thr, 128 rows (16a x 8b) x 128 cols, K=1024, Kc=32 --------
// grid 8192 = 512 bt x 4 at x 4 cb; 4 waves (2M x 2N), wave tile 64x64, acc[4][4]=64 AGPR.
// __launch_bounds__(256,3) -> ~150 regs -> 3 blocks/CU: independent blocks decouple
// barriers (the m97 mechanism R6-R8's 1-block/CU occupancy could not express).
// In-register A-gen; B frag-packed so DMA order == read order (no swizzle, 0 conflicts).
__global__ __launch_bounds__(256, 3) void kmain(
        const unsigned short* __restrict__ Gt,    // [32][4096][32]
        const unsigned short* __restrict__ caT2,  // [4][32][16][32]
        const unsigned short* __restrict__ W2f,   // frag-packed 8KB tiles [kc][cb]
        const float* __restrict__ nb,
        const float* __restrict__ b2, const float* __restrict__ Wq,
        const float* __restrict__ bq, float* __restrict__ out) {
    int bid = blockIdx.x;
    int cb = bid & 3;
    int at = (bid >> 2) & 3;
    int bt = bid >> 4;

    __shared__ __align__(16) unsigned short Bs[2][4096];   // 2 x 8 KB
    __shared__ float invnh[128];
    __shared__ float qred[128][2];

    int t = threadIdx.x;
    int lane = t & 63, w = t >> 6;
    int wr = w >> 1, wc = w & 1;
    int l15 = lane & 15, l4 = lane >> 4;

    // A-gen addressing: G row depends only on (l15&7); ca rows at constant mt offsets.
    const unsigned short* gG = Gt + ((size_t)(bt * 8 + (l15 & 7))) * 32 + l4 * 8;
    const unsigned short* gC = caT2 + (size_t)at * 16384 + (wr * 8 + (l15 >> 3)) * 32 + l4 * 8;

    float sqa[4] = {0.f, 0.f, 0.f, 0.f};
    f32x4 acc[4][4] = {};
    bf16x8 g_v, c_v0, c_v1, c_v2, c_v3;

    auto fillB = [&](int kc, int s) {
        const char* gs = (const char*)W2f + (((size_t)(kc * 4 + cb)) << 13) + w * 2048 + (lane << 4);
        char* ld = (char*)Bs[s] + w * 2048 + (lane << 4);
        async_copy16(gs, ld);
        async_copy16(gs + 1024, ld + 1024);
    };
    auto loadGC = [&]() {
        g_v = *(const bf16x8*)gG;
        c_v0 = *(const bf16x8*)(gC);
        c_v1 = *(const bf16x8*)(gC + 64);
        c_v2 = *(const bf16x8*)(gC + 128);
        c_v3 = *(const bf16x8*)(gC + 192);
    };

    // prologue
    loadGC();
    fillB(0, 0);

    // B frag base: frag f = wc*4 + nt, at f*512 + lane*8 (contiguous, conflict-free)
    const int boff = (wc * 4) * 512 + lane * 8;

    for (int kc = 0; kc < 32; ++kc) {
        int s = kc & 1;
        __syncthreads();   // Bs[s] + g/c(kc) regs ready (issued last iter; barrier drains vmcnt)

        // ---- A-gen in registers: u = relu(G' + ca), 4 m-frags; sq on wc==0 waves ----
        bf16x8 af0, af1, af2, af3;
        {
            const unsigned* gd = (const unsigned*)&g_v;
            const unsigned* cd0 = (const unsigned*)&c_v0;
            const unsigned* cd1 = (const unsigned*)&c_v1;
            const unsigned* cd2 = (const unsigned*)&c_v2;
            const unsigned* cd3 = (const unsigned*)&c_v3;
            unsigned o0[4], o1[4], o2[4], o3[4];
#pragma unroll
            for (int p = 0; p < 4; p++) {
                float gl0 = bflo(gd[p]), gl1 = bfhi(gd[p]);
                float u00 = fmaxf(gl0 + bflo(cd0[p]), 0.f);
                float u01 = fmaxf(gl1 + bfhi(cd0[p]), 0.f);
                float u10 = fmaxf(gl0 + bflo(cd1[p]), 0.f);
                float u11 = fmaxf(gl1 + bfhi(cd1[p]), 0.f);
                float u20 = fmaxf(gl0 + bflo(cd2[p]), 0.f);
                float u21 = fmaxf(gl1 + bfhi(cd2[p]), 0.f);
                float u30 = fmaxf(gl0 + bflo(cd3[p]), 0.f);
                float u31 = fmaxf(gl1 + bfhi(cd3[p]), 0.f);
                o0[p] = packtrunc(u00, u01);
                o1[p] = packtrunc(u10, u11);
                o2[p] = packtrunc(u20, u21);
                o3[p] = packtrunc(u30, u31);
                if (wc == 0) {   // wave-uniform
                    sqa[0] = fmaf(u00, u00, fmaf(u01, u01, sqa[0]));
                    sqa[1] = fmaf(u10, u10, fmaf(u11, u11, sqa[1]));
                    sqa[2] = fmaf(u20, u20, fmaf(u21, u21, sqa[2]));
                    sqa[3] = fmaf(u30, u30, fmaf(u31, u31, sqa[3]));
                }
            }
            af0 = *(bf16x8*)o0; af1 = *(bf16x8*)o1; af2 = *(bf16x8*)o2; af3 = *(bf16x8*)o3;
        }

        if (kc < 31) {   // prefetch for kc+1; consumed only after next barrier (no mid-iter waits)
            fillB(kc + 1, s ^ 1);
            gG += (size_t)NB * 32;
            gC += 512;
            loadGC();
        }

        // ---- MFMA(kc): wave tile 64 x 64 ----
        const unsigned short* bb2 = Bs[s] + boff;
        bf16x8 bfr[4];
#pragma unroll
        for (int nt = 0; nt < 4; nt++)
            bfr[nt] = *(const bf16x8*)(bb2 + nt * 512);
#pragma unroll
        for (int nt = 0; nt < 4; nt++) {
            acc[0][nt] = __builtin_amdgcn_mfma_f32_16x16x32_bf16(af0, bfr[nt], acc[0][nt], 0, 0, 0);
            acc[1][nt] = __builtin_amdgcn_mfma_f32_16x16x32_bf16(af1, bfr[nt], acc[1][nt], 0, 0, 0);
            acc[2][nt] = __builtin_amdgcn_mfma_f32_16x16x32_bf16(af2, bfr[nt], acc[2][nt], 0, 0, 0);
            acc[3][nt] = __builtin_amdgcn_mfma_f32_16x16x32_bf16(af3, bfr[nt], acc[3][nt], 0, 0, 0);
        }
    }

    // ---- ||u|| per row (wc==0 waves hold sq partials over l4) ----
#pragma unroll
    for (int mt = 0; mt < 4; mt++) {
        float sv = sqa[mt];
        sv += __shfl_xor(sv, 16, 64);
        sv += __shfl_xor(sv, 32, 64);
        if (wc == 0 && l4 == 0) {
            int R = wr * 64 + mt * 16 + l15;
            invnh[R] = 1.0f / (sqrtf(sv) + 1e-8f * nb[bt * 8 + (l15 & 7)]);
        }
    }
    __syncthreads();

    // ---- epilogue: z = acc*invnh + b2; relu; q-partial over this block's 128 cols ----
    float wqv[4], b2v[4];
#pragma unroll
    for (int nt = 0; nt < 4; nt++) {
        int o = cb * 128 + wc * 64 + nt * 16 + l15;
        wqv[nt] = Wq[o]; b2v[nt] = b2[o];
    }
#pragma unroll
    for (int mt = 0; mt < 4; mt++) {
#pragma unroll
        for (int i = 0; i < 4; i++) {
            int R = wr * 64 + mt * 16 + l4 * 4 + i;
            float inv = invnh[R];
            float qp = 0.f;
#pragma unroll
            for (int nt = 0; nt < 4; nt++) {
                float z = fmaf(acc[mt][nt][i], inv, b2v[nt]);
                z = fmaxf(z, 0.f);
                qp = fmaf(z, wqv[nt], qp);
            }
            qp += __shfl_xor(qp, 1, 64);
            qp += __shfl_xor(qp, 2, 64);
            qp += __shfl_xor(qp, 4, 64);
            qp += __shfl_xor(qp, 8, 64);
            if (l15 == 0) qred[R][wc] = qp;
        }
    }
    __syncthreads();
    if (t < 128) {
        float qv = qred[t][0] + qred[t][1];
        if (cb == 0) qv += bq[0];
        int aa = at * 16 + (t >> 3);
        int bo = bt * 8 + (t & 7);
        atomicAdd(out + (size_t)bo * NA + aa, qv);
    }
}

extern "C" void kernel_launch(void* const* d_in, const int* in_sizes, int n_in,
                              void* d_out, int out_size, void* d_ws, size_t ws_size,
                              hipStream_t stream) {
    const float* states = (const float*)d_in[0];
    const float* W1     = (const float*)d_in[1];
    const float* b1     = (const float*)d_in[2];
    const float* W2     = (const float*)d_in[3];
    const float* b2     = (const float*)d_in[4];
    const float* Wq     = (const float*)d_in[5];
    const float* bq     = (const float*)d_in[6];
    float* out = (float*)d_out;

    char* ws = (char*)d_ws;
    unsigned short* Gt   = (unsigned short*)ws;                              // 8 MB
    unsigned short* W2f  = (unsigned short*)(ws + (8u << 20));               // 1 MB
    unsigned short* caT2 = (unsigned short*)(ws + (9u << 20));               // 128 KB
    float*          nbp  = (float*)(ws + (9u << 20) + (128u << 10));         // 16 KB

    hipMemsetAsync(d_out, 0, (size_t)out_size * sizeof(float), stream);
    knorm<<<NB, 64, 0, stream>>>(states, nbp);
    kprep<<<2304, 256, 0, stream>>>(W1, W2, W2f, caT2);
    kgemm1<<<256, 256, 0, stream>>>(states, W1, b1, nbp, Gt);
    kmain<<<8192, 256, 0, stream>>>(Gt, caT2, W2f, nbp, b2, Wq, bq, out);
}

// Round 10
// 456.065 us; speedup vs baseline: 1.2809x; 1.2809x over previous
//
#include <hip/hip_runtime.h>
#include <stdint.h>

#define NB 4096
#define NS 512
#define NA 64
#define NH1 1024
#define NH2 512

typedef __attribute__((ext_vector_type(8))) short bf16x8;
typedef __attribute__((ext_vector_type(4))) float f32x4;

__device__ __forceinline__ unsigned short f2bf(float f) {
    union { float f; unsigned u; } v; v.f = f;
    return (unsigned short)((v.u + 0x8000u) >> 16);   // round-half-up bf16
}
__device__ __forceinline__ float bf2f(unsigned short h) {
    union { float f; unsigned u; } v; v.u = ((unsigned)h) << 16;
    return v.f;
}
__device__ __forceinline__ float bflo(unsigned u) {
    union { unsigned u; float f; } v; v.u = u << 16; return v.f;
}
__device__ __forceinline__ float bfhi(unsigned u) {
    union { unsigned u; float f; } v; v.u = u & 0xFFFF0000u; return v.f;
}
// truncating pack of two f32 -> bf16x2 (bias cancels in u/||u||): 1 v_perm
__device__ __forceinline__ unsigned packtrunc(float lo, float hi) {
    union { float f; unsigned u; } a, b; a.f = lo; b.f = hi;
    return __builtin_amdgcn_perm(b.u, a.u, 0x07060302u);
}
__device__ __forceinline__ void split2(float x, unsigned short& h, unsigned short& l) {
    unsigned short hh = f2bf(x);
    h = hh;
    l = f2bf(x - bf2f(hh));
}
__device__ __forceinline__ void async_copy16(const void* g, void* l) {
    __builtin_amdgcn_global_load_lds((const __attribute__((address_space(1))) void*)g,
                                     (__attribute__((address_space(3))) void*)l, 16, 0, 0);
}

// ---------------- P0: nb[b] = sqrt(||s_b||^2 + 1) + 1e-8 ----------------
__global__ void knorm(const float* __restrict__ S, float* __restrict__ nb) {
    int b = blockIdx.x; int l = threadIdx.x; // one wave
    const float* row = S + b * NS;
    float s = 0.f;
    for (int k = l; k < NS; k += 64) { float v = row[k]; s = fmaf(v, v, s); }
    for (int off = 32; off; off >>= 1) s += __shfl_down(s, off, 64);
    if (l == 0) nb[b] = sqrtf(s + 1.0f) + 1e-8f;
}

// ---------------- P1: W2f (frag-packed 16KB per (cb,kc) tile) + caT2 ----------------
// W2f short idx i = ((cb*32 + kc)*8192) + f*512 + l*8 + j, f in 0..15:
//   value = W2[cb*256 + (f>>3)*128 + (f&7)*16 + (l&15)][kc*32 + (l>>4)*8 + j]
// (exact read order of kmain's B-fragments: DMA order == read order, no swizzle)
// caT2[at(8)][kc(32)][a(8)][k(32)] = W1[(kc*32+kk)*576 + 512 + at*8 + a]
__global__ void kprep(const float* __restrict__ W1, const float* __restrict__ W2,
                      unsigned short* __restrict__ W2f, unsigned short* __restrict__ caT2) {
    int i = blockIdx.x * 256 + threadIdx.x;
    if (i < 524288) {
        int j = i & 7; int l = (i >> 3) & 63; int f = (i >> 9) & 15;
        int kc = (i >> 13) & 31; int cbb = i >> 18;
        int n = cbb * 256 + (f >> 3) * 128 + (f & 7) * 16 + (l & 15);
        int k = kc * 32 + (l >> 4) * 8 + j;
        W2f[i] = f2bf(W2[(size_t)n * NH1 + k]);
    } else {
        int j2 = i - 524288;                 // 65536 entries
        int kk = j2 & 31; int a = (j2 >> 5) & 7;
        int kc = (j2 >> 8) & 31; int att = j2 >> 13;
        int o = kc * 32 + kk;
        caT2[j2] = f2bf(W1[(size_t)o * 576 + 512 + att * 8 + a]);
    }
}

// ---------------- P2: Gt'[kc][b][32k] bf16 = s@W1s^T + b1*nb  (split-bf16, 3 GEMMs) ----
__global__ __launch_bounds__(256) void kgemm1(
        const float* __restrict__ Sm, const float* __restrict__ W1,
        const float* __restrict__ b1, const float* __restrict__ nb,
        unsigned short* __restrict__ Gt) {
    const int m0 = (blockIdx.x >> 3) * 128;
    const int n0 = (blockIdx.x & 7) * 128;
    __shared__ unsigned short Ah[128][40], Al[128][40], Bh[128][40], Bl[128][40];
    int t = threadIdx.x;
    int lane = t & 63, wave = t >> 6;
    int wr = wave >> 1, wc = wave & 1;
    int qd = lane >> 4, cl = lane & 15;
    int r = t >> 1, seg = t & 1;
    f32x4 acc[4][4] = {};

    for (int k0 = 0; k0 < 512; k0 += 32) {
        {
            const float4* as4 = (const float4*)(Sm + (size_t)(m0 + r) * NS + k0 + seg * 16);
            const float4* bs4 = (const float4*)(W1 + (size_t)(n0 + r) * 576 + k0 + seg * 16);
            unsigned* ah = (unsigned*)&Ah[r][seg * 16];
            unsigned* al = (unsigned*)&Al[r][seg * 16];
            unsigned* bh = (unsigned*)&Bh[r][seg * 16];
            unsigned* bl = (unsigned*)&Bl[r][seg * 16];
#pragma unroll
            for (int v = 0; v < 4; v++) {
                float4 fa = as4[v];
                unsigned short h0,h1,h2,h3,l0,l1,l2,l3;
                split2(fa.x,h0,l0); split2(fa.y,h1,l1); split2(fa.z,h2,l2); split2(fa.w,h3,l3);
                ah[v*2]   = (unsigned)h0 | ((unsigned)h1 << 16);
                ah[v*2+1] = (unsigned)h2 | ((unsigned)h3 << 16);
                al[v*2]   = (unsigned)l0 | ((unsigned)l1 << 16);
                al[v*2+1] = (unsigned)l2 | ((unsigned)l3 << 16);
                float4 fb = bs4[v];
                split2(fb.x,h0,l0); split2(fb.y,h1,l1); split2(fb.z,h2,l2); split2(fb.w,h3,l3);
                bh[v*2]   = (unsigned)h0 | ((unsigned)h1 << 16);
                bh[v*2+1] = (unsigned)h2 | ((unsigned)h3 << 16);
                bl[v*2]   = (unsigned)l0 | ((unsigned)l1 << 16);
                bl[v*2+1] = (unsigned)l2 | ((unsigned)l3 << 16);
            }
        }
        __syncthreads();
        bf16x8 a_h[4], a_l[4], b_h[4], b_l[4];
#pragma unroll
        for (int mt = 0; mt < 4; mt++) {
            a_h[mt] = *(const bf16x8*)&Ah[wr*64 + mt*16 + cl][qd*8];
            a_l[mt] = *(const bf16x8*)&Al[wr*64 + mt*16 + cl][qd*8];
        }
#pragma unroll
        for (int nt = 0; nt < 4; nt++) {
            b_h[nt] = *(const bf16x8*)&Bh[wc*64 + nt*16 + cl][qd*8];
            b_l[nt] = *(const bf16x8*)&Bl[wc*64 + nt*16 + cl][qd*8];
        }
#pragma unroll
        for (int mt = 0; mt < 4; mt++)
#pragma unroll
            for (int nt = 0; nt < 4; nt++) {
                acc[mt][nt] = __builtin_amdgcn_mfma_f32_16x16x32_bf16(a_h[mt], b_h[nt], acc[mt][nt], 0, 0, 0);
                acc[mt][nt] = __builtin_amdgcn_mfma_f32_16x16x32_bf16(a_h[mt], b_l[nt], acc[mt][nt], 0, 0, 0);
                acc[mt][nt] = __builtin_amdgcn_mfma_f32_16x16x32_bf16(a_l[mt], b_h[nt], acc[mt][nt], 0, 0, 0);
            }
        __syncthreads();
    }
#pragma unroll
    for (int mt = 0; mt < 4; mt++)
#pragma unroll
        for (int i = 0; i < 4; i++) {
            int m = m0 + wr*64 + mt*16 + qd*4 + i;
            float nbv = nb[m];
#pragma unroll
            for (int nt = 0; nt < 4; nt++) {
                int n = n0 + wc*64 + nt*16 + cl;
                float val = fmaf(b1[nt*16+cl+n0+wc*64], nbv, acc[mt][nt][i]);
                Gt[((size_t)(n >> 5) * NB + m) * 32 + (n & 31)] = f2bf(val);
            }
        }
}

// ---------------- Main: 256 thr, 64 rows (8a x 8b) x 256 cols, K=1024, Kc=32 ----------
// grid 8192 = 512 bt x 8 at x 2 cb. Waves 2x2: wr = row half(32), wc = col half(128).
// Wave tile 32x128, acc[2][8] = 64 AGPR -> ~144 regs -> 3 blocks/CU (m97 overlap).
// A staged via LDS (gen once/block: redundancy = col-split = 2, VALU ~95 us-equiv < MFMA floor).
// B frag-packed (DMA order == read order, 0 conflicts). 1-barrier pipeline (R9 order).
__global__ __launch_bounds__(256, 3) void kmain(
        const unsigned short* __restrict__ Gt,    // [32][4096][32]
        const unsigned short* __restrict__ caT2,  // [8][32][8][32]
        const unsigned short* __restrict__ W2f,   // frag-packed 16KB tiles [cb][kc]
        const float* __restrict__ nb,
        const float* __restrict__ b2, const float* __restrict__ Wq,
        const float* __restrict__ bq, float* __restrict__ out) {
    int bid = blockIdx.x;
    int cb = bid & 1;
    int at = (bid >> 1) & 7;
    int bt = bid >> 4;

    __shared__ __align__(16) unsigned short As[2][64][40];   // 2 x 5 KB, pad->2-way only
    __shared__ __align__(16) unsigned short Bs[2][8192];     // 2 x 16 KB frag-packed
    __shared__ float invnh[64];
    __shared__ float qred[64][2];

    int t = threadIdx.x;
    int lane = t & 63, w = t >> 6;
    int wr = w >> 1, wc = w & 1;
    int l15 = lane & 15, l4 = lane >> 4;

    // A-gen role: thread owns row (t>>2) = a_loc*8+b_loc, k-octet (t&3); 8 elems/iter
    int row = t >> 2, kd = t & 3;
    const unsigned short* gG = Gt + ((size_t)(bt * 8 + (row & 7))) * 32 + kd * 8;
    const unsigned short* gC = caT2 + (size_t)at * 8192 + (row >> 3) * 32 + kd * 8;

    float sq = 0.f;
    f32x4 acc[2][8] = {};
    bf16x8 g_v, c_v;

    auto fillB = [&](int kc, int s) {
        const char* gs = (const char*)W2f + (((size_t)(cb * 32 + kc)) << 14) + (t << 4);
        char* ld = (char*)Bs[s] + (t << 4);
        async_copy16(gs, ld);
        async_copy16(gs + 4096, ld + 4096);
        async_copy16(gs + 8192, ld + 8192);
        async_copy16(gs + 12288, ld + 12288);
    };
    auto loadGC = [&]() {
        g_v = *(const bf16x8*)gG;
        c_v = *(const bf16x8*)gC;
    };
    auto agen = [&](int s) {   // u = relu(G' + ca) for 8 elems -> As[s][row][kd*8..]
        const unsigned* gd = (const unsigned*)&g_v;
        const unsigned* cd = (const unsigned*)&c_v;
        unsigned ow[4];
#pragma unroll
        for (int p = 0; p < 4; p++) {
            float u0 = fmaxf(bflo(gd[p]) + bflo(cd[p]), 0.f);
            float u1 = fmaxf(bfhi(gd[p]) + bfhi(cd[p]), 0.f);
            sq = fmaf(u0, u0, sq);
            sq = fmaf(u1, u1, sq);
            ow[p] = packtrunc(u0, u1);
        }
        *(bf16x8*)&As[s][row][kd * 8] = *(bf16x8*)ow;
    };

    // prologue: u(0)->As[0], B(0)->Bs[0], prefetch g/c(1)
    loadGC();
    agen(0);
    fillB(0, 0);
    gG += (size_t)NB * 32;
    gC += 256;
    loadGC();

    // B frag base: frag f = wc*8 + nt at f*512 shorts; lane reads lane*8 (contiguous)
    const int boff = (wc * 8) * 512 + lane * 8;

    for (int kc = 0; kc < 32; ++kc) {
        int s = kc & 1;
        __syncthreads();   // As[s]/Bs[s]/g_v ready (all issued last iter; barrier drains)

        if (kc < 31) {
            agen(s ^ 1);            // u(kc+1) -> other A slot (consumes g/c regs first)
            fillB(kc + 1, s ^ 1);   // B(kc+1) DMA, in flight until next barrier
            if (kc < 30) {          // g/c(kc+2) register prefetch
                gG += (size_t)NB * 32;
                gC += 256;
                loadGC();
            }
        }

        // ---- MFMA(kc): wave tile 32 rows x 128 cols ----
        bf16x8 af0 = *(const bf16x8*)&As[s][wr * 32 + l15][l4 * 8];
        bf16x8 af1 = *(const bf16x8*)&As[s][wr * 32 + 16 + l15][l4 * 8];
        const unsigned short* bb = Bs[s] + boff;
        bf16x8 bfr[8];
#pragma unroll
        for (int nt = 0; nt < 8; nt++)
            bfr[nt] = *(const bf16x8*)(bb + nt * 512);
#pragma unroll
        for (int nt = 0; nt < 8; nt++) {
            acc[0][nt] = __builtin_amdgcn_mfma_f32_16x16x32_bf16(af0, bfr[nt], acc[0][nt], 0, 0, 0);
            acc[1][nt] = __builtin_amdgcn_mfma_f32_16x16x32_bf16(af1, bfr[nt], acc[1][nt], 0, 0, 0);
        }
    }

    // ---- ||u|| per row: reduce over 4 kd threads (consecutive lanes) ----
    sq += __shfl_xor(sq, 1, 64);
    sq += __shfl_xor(sq, 2, 64);
    if (kd == 0) invnh[row] = 1.0f / (sqrtf(sq) + 1e-8f * nb[bt * 8 + (row & 7)]);
    __syncthreads();

    // ---- epilogue: z = acc*invnh + b2; relu; q-partial over this block's 256 cols ----
    float wqv[8], b2v[8];
#pragma unroll
    for (int nt = 0; nt < 8; nt++) {
        int o = cb * 256 + wc * 128 + nt * 16 + l15;
        wqv[nt] = Wq[o]; b2v[nt] = b2[o];
    }
#pragma unroll
    for (int mt = 0; mt < 2; mt++) {
#pragma unroll
        for (int i = 0; i < 4; i++) {
            int R = wr * 32 + mt * 16 + l4 * 4 + i;
            float inv = invnh[R];
            float qp = 0.f;
#pragma unroll
            for (int nt = 0; nt < 8; nt++) {
                float z = fmaf(acc[mt][nt][i], inv, b2v[nt]);
                z = fmaxf(z, 0.f);
                qp = fmaf(z, wqv[nt], qp);
            }
            qp += __shfl_xor(qp, 1, 64);
            qp += __shfl_xor(qp, 2, 64);
            qp += __shfl_xor(qp, 4, 64);
            qp += __shfl_xor(qp, 8, 64);
            if (l15 == 0) qred[R][wc] = qp;
        }
    }
    __syncthreads();
    if (t < 64) {
        float qv = qred[t][0] + qred[t][1];
        if (cb == 0) qv += bq[0];
        int aa = at * 8 + (t >> 3);
        int bo = bt * 8 + (t & 7);
        atomicAdd(out + (size_t)bo * NA + aa, qv);
    }
}

extern "C" void kernel_launch(void* const* d_in, const int* in_sizes, int n_in,
                              void* d_out, int out_size, void* d_ws, size_t ws_size,
                              hipStream_t stream) {
    const float* states = (const float*)d_in[0];
    const float* W1     = (const float*)d_in[1];
    const float* b1     = (const float*)d_in[2];
    const float* W2     = (const float*)d_in[3];
    const float* b2     = (const float*)d_in[4];
    const float* Wq     = (const float*)d_in[5];
    const float* bq     = (const float*)d_in[6];
    float* out = (float*)d_out;

    char* ws = (char*)d_ws;
    unsigned short* Gt   = (unsigned short*)ws;                              // 8 MB
    unsigned short* W2f  = (unsigned short*)(ws + (8u << 20));               // 1 MB
    unsigned short* caT2 = (unsigned short*)(ws + (9u << 20));               // 128 KB
    float*          nbp  = (float*)(ws + (9u << 20) + (128u << 10));         // 16 KB

    hipMemsetAsync(d_out, 0, (size_t)out_size * sizeof(float), stream);
    knorm<<<NB, 64, 0, stream>>>(states, nbp);
    kprep<<<2304, 256, 0, stream>>>(W1, W2, W2f, caT2);
    kgemm1<<<256, 256, 0, stream>>>(states, W1, b1, nbp, Gt);
    kmain<<<8192, 256, 0, stream>>>(Gt, caT2, W2f, nbp, b2, Wq, bq, out);
}

// Round 11
// 435.072 us; speedup vs baseline: 1.3427x; 1.0483x over previous
//
#include <hip/hip_runtime.h>
#include <stdint.h>

#define NB 4096
#define NS 512
#define NA 64
#define NH1 1024
#define NH2 512

typedef __attribute__((ext_vector_type(8))) short bf16x8;
typedef __attribute__((ext_vector_type(4))) float f32x4;

__device__ __forceinline__ unsigned short f2bf(float f) {
    union { float f; unsigned u; } v; v.f = f;
    return (unsigned short)((v.u + 0x8000u) >> 16);   // round-half-up bf16
}
__device__ __forceinline__ float bf2f(unsigned short h) {
    union { float f; unsigned u; } v; v.u = ((unsigned)h) << 16;
    return v.f;
}
__device__ __forceinline__ float bflo(unsigned u) {
    union { unsigned u; float f; } v; v.u = u << 16; return v.f;
}
__device__ __forceinline__ float bfhi(unsigned u) {
    union { unsigned u; float f; } v; v.u = u & 0xFFFF0000u; return v.f;
}
// truncating pack of two f32 -> bf16x2 (bias cancels in u/||u||): 1 v_perm
__device__ __forceinline__ unsigned packtrunc(float lo, float hi) {
    union { float f; unsigned u; } a, b; a.f = lo; b.f = hi;
    return __builtin_amdgcn_perm(b.u, a.u, 0x07060302u);
}
__device__ __forceinline__ void split2(float x, unsigned short& h, unsigned short& l) {
    unsigned short hh = f2bf(x);
    h = hh;
    l = f2bf(x - bf2f(hh));
}
__device__ __forceinline__ void async_copy16(const void* g, void* l) {
    __builtin_amdgcn_global_load_lds((const __attribute__((address_space(1))) void*)g,
                                     (__attribute__((address_space(3))) void*)l, 16, 0, 0);
}

// ---------------- P0: nb[b] = sqrt(||s_b||^2 + 1) + 1e-8 ----------------
__global__ void knorm(const float* __restrict__ S, float* __restrict__ nb) {
    int b = blockIdx.x; int l = threadIdx.x; // one wave
    const float* row = S + b * NS;
    float s = 0.f;
    for (int k = l; k < NS; k += 64) { float v = row[k]; s = fmaf(v, v, s); }
    for (int off = 32; off; off >>= 1) s += __shfl_down(s, off, 64);
    if (l == 0) nb[b] = sqrtf(s + 1.0f) + 1e-8f;
}

// ---------------- P1: W2f (frag-packed 16KB per (cb,kc) tile) + caT2 ----------------
// W2f short idx i = ((cb*32 + kc)*16 + f)*512 + l*8 + j, f in 0..15 (= wc*8 + nt):
//   value = W2[cb*256 + (f>>3)*128 + (f&7)*16 + (l&15)][kc*32 + (l>>4)*8 + j]
// (exact read order of kmain's B-fragments: DMA order == read order, no swizzle)
// caT2[at(4)][kc(32)][a(16)][k(32)] = W1[(kc*32+kk)*576 + 512 + at*16 + a]
__global__ void kprep(const float* __restrict__ W1, const float* __restrict__ W2,
                      unsigned short* __restrict__ W2f, unsigned short* __restrict__ caT2) {
    int i = blockIdx.x * 256 + threadIdx.x;
    if (i < 524288) {
        int j = i & 7; int l = (i >> 3) & 63; int f = (i >> 9) & 15;
        int kc = (i >> 13) & 31; int cbb = i >> 18;
        int n = cbb * 256 + (f >> 3) * 128 + (f & 7) * 16 + (l & 15);
        int k = kc * 32 + (l >> 4) * 8 + j;
        W2f[i] = f2bf(W2[(size_t)n * NH1 + k]);
    } else {
        int j2 = i - 524288;                 // 65536 entries
        int kk = j2 & 31; int a_loc = (j2 >> 5) & 15;
        int kc = (j2 >> 9) & 31; int att = j2 >> 14;
        int o = kc * 32 + kk;
        caT2[j2] = f2bf(W1[(size_t)o * 576 + 512 + att * 16 + a_loc]);
    }
}

// ---------------- P2: Gt'[kc][b][32k] bf16 = s@W1s^T + b1*nb  (split-bf16, 3 GEMMs) ----
__global__ __launch_bounds__(256) void kgemm1(
        const float* __restrict__ Sm, const float* __restrict__ W1,
        const float* __restrict__ b1, const float* __restrict__ nb,
        unsigned short* __restrict__ Gt) {
    const int m0 = (blockIdx.x >> 3) * 128;
    const int n0 = (blockIdx.x & 7) * 128;
    __shared__ unsigned short Ah[128][40], Al[128][40], Bh[128][40], Bl[128][40];
    int t = threadIdx.x;
    int lane = t & 63, wave = t >> 6;
    int wr = wave >> 1, wc = wave & 1;
    int qd = lane >> 4, cl = lane & 15;
    int r = t >> 1, seg = t & 1;
    f32x4 acc[4][4] = {};

    for (int k0 = 0; k0 < 512; k0 += 32) {
        {
            const float4* as4 = (const float4*)(Sm + (size_t)(m0 + r) * NS + k0 + seg * 16);
            const float4* bs4 = (const float4*)(W1 + (size_t)(n0 + r) * 576 + k0 + seg * 16);
            unsigned* ah = (unsigned*)&Ah[r][seg * 16];
            unsigned* al = (unsigned*)&Al[r][seg * 16];
            unsigned* bh = (unsigned*)&Bh[r][seg * 16];
            unsigned* bl = (unsigned*)&Bl[r][seg * 16];
#pragma unroll
            for (int v = 0; v < 4; v++) {
                float4 fa = as4[v];
                unsigned short h0,h1,h2,h3,l0,l1,l2,l3;
                split2(fa.x,h0,l0); split2(fa.y,h1,l1); split2(fa.z,h2,l2); split2(fa.w,h3,l3);
                ah[v*2]   = (unsigned)h0 | ((unsigned)h1 << 16);
                ah[v*2+1] = (unsigned)h2 | ((unsigned)h3 << 16);
                al[v*2]   = (unsigned)l0 | ((unsigned)l1 << 16);
                al[v*2+1] = (unsigned)l2 | ((unsigned)l3 << 16);
                float4 fb = bs4[v];
                split2(fb.x,h0,l0); split2(fb.y,h1,l1); split2(fb.z,h2,l2); split2(fb.w,h3,l3);
                bh[v*2]   = (unsigned)h0 | ((unsigned)h1 << 16);
                bh[v*2+1] = (unsigned)h2 | ((unsigned)h3 << 16);
                bl[v*2]   = (unsigned)l0 | ((unsigned)l1 << 16);
                bl[v*2+1] = (unsigned)l2 | ((unsigned)l3 << 16);
            }
        }
        __syncthreads();
        bf16x8 a_h[4], a_l[4], b_h[4], b_l[4];
#pragma unroll
        for (int mt = 0; mt < 4; mt++) {
            a_h[mt] = *(const bf16x8*)&Ah[wr*64 + mt*16 + cl][qd*8];
            a_l[mt] = *(const bf16x8*)&Al[wr*64 + mt*16 + cl][qd*8];
        }
#pragma unroll
        for (int nt = 0; nt < 4; nt++) {
            b_h[nt] = *(const bf16x8*)&Bh[wc*64 + nt*16 + cl][qd*8];
            b_l[nt] = *(const bf16x8*)&Bl[wc*64 + nt*16 + cl][qd*8];
        }
#pragma unroll
        for (int mt = 0; mt < 4; mt++)
#pragma unroll
            for (int nt = 0; nt < 4; nt++) {
                acc[mt][nt] = __builtin_amdgcn_mfma_f32_16x16x32_bf16(a_h[mt], b_h[nt], acc[mt][nt], 0, 0, 0);
                acc[mt][nt] = __builtin_amdgcn_mfma_f32_16x16x32_bf16(a_h[mt], b_l[nt], acc[mt][nt], 0, 0, 0);
                acc[mt][nt] = __builtin_amdgcn_mfma_f32_16x16x32_bf16(a_l[mt], b_h[nt], acc[mt][nt], 0, 0, 0);
            }
        __syncthreads();
    }
#pragma unroll
    for (int mt = 0; mt < 4; mt++)
#pragma unroll
        for (int i = 0; i < 4; i++) {
            int m = m0 + wr*64 + mt*16 + qd*4 + i;
            float nbv = nb[m];
#pragma unroll
            for (int nt = 0; nt < 4; nt++) {
                int n = n0 + wc*64 + nt*16 + cl;
                float val = fmaf(b1[n], nbv, acc[mt][nt][i]);
                Gt[((size_t)(n >> 5) * NB + m) * 32 + (n & 31)] = f2bf(val);
            }
        }
}

// ---------------- Main: 256 thr, 128 rows (16a x 8b) x 256 cols, K=1024, Kc=32 --------
// grid 4096 = 512 bt x 4 at x 2 cb; waves 2x2, wave tile 64x128, acc[4][8]=128 AGPR.
// __launch_bounds__(256,2): ~230 unified regs -> 2 waves/SIMD -> 2 INDEPENDENT blocks/CU
// (R6's economics — redundancy-2 A-gen, 2.1 GB B L2 traffic — plus barrier decoupling
// that R6's single 512-thr block could not express).
__global__ __launch_bounds__(256, 2) void kmain(
        const unsigned short* __restrict__ Gt,    // [32][4096][32]
        const unsigned short* __restrict__ caT2,  // [4][32][16][32]
        const unsigned short* __restrict__ W2f,   // frag-packed 16KB tiles [cb][kc]
        const float* __restrict__ nb,
        const float* __restrict__ b2, const float* __restrict__ Wq,
        const float* __restrict__ bq, float* __restrict__ out) {
    int bid = blockIdx.x;
    int cb = bid & 1;
    int at = (bid >> 1) & 3;
    int bt = bid >> 3;

    __shared__ __align__(16) unsigned short As[2][128][40];  // 2 x 10 KB, +8 pad
    __shared__ __align__(16) unsigned short Bs[2][8192];     // 2 x 16 KB frag-packed
    __shared__ float invnh[128];
    __shared__ float qred[128][2];

    int t = threadIdx.x;
    int lane = t & 63, w = t >> 6;
    int wr = w >> 1, wc = w & 1;
    int l15 = lane & 15, l4 = lane >> 4;

    // A-gen role: thread owns row (t>>1) = a_loc*8+b_loc and k-16-half (t&1); 16 elems/iter
    int row = t >> 1, kd = t & 1;
    const unsigned short* gG = Gt + ((size_t)(bt * 8 + (row & 7))) * 32 + kd * 16;
    const unsigned short* gC = caT2 + (size_t)at * 16384 + (row >> 3) * 32 + kd * 16;

    float sq = 0.f;
    f32x4 acc[4][8] = {};
    bf16x8 g_v0, g_v1, c_v0, c_v1;

    auto fillB = [&](int kc, int s) {
        const char* gs = (const char*)W2f + (((size_t)(cb * 32 + kc)) << 14) + (t << 4);
        char* ld = (char*)Bs[s] + (t << 4);
        async_copy16(gs, ld);
        async_copy16(gs + 4096, ld + 4096);
        async_copy16(gs + 8192, ld + 8192);
        async_copy16(gs + 12288, ld + 12288);
    };
    auto loadGC = [&]() {
        g_v0 = *(const bf16x8*)gG;
        g_v1 = *(const bf16x8*)(gG + 8);
        c_v0 = *(const bf16x8*)gC;
        c_v1 = *(const bf16x8*)(gC + 8);
    };
    auto agen = [&](int s) {   // u = relu(G' + ca) for 16 elems -> As[s][row][kd*16..]
        unsigned ow0[4], ow1[4];
        const unsigned* gd0 = (const unsigned*)&g_v0;
        const unsigned* cd0 = (const unsigned*)&c_v0;
        const unsigned* gd1 = (const unsigned*)&g_v1;
        const unsigned* cd1 = (const unsigned*)&c_v1;
#pragma unroll
        for (int p = 0; p < 4; p++) {
            float u0 = fmaxf(bflo(gd0[p]) + bflo(cd0[p]), 0.f);
            float u1 = fmaxf(bfhi(gd0[p]) + bfhi(cd0[p]), 0.f);
            float u2 = fmaxf(bflo(gd1[p]) + bflo(cd1[p]), 0.f);
            float u3 = fmaxf(bfhi(gd1[p]) + bfhi(cd1[p]), 0.f);
            sq = fmaf(u0, u0, sq);
            sq = fmaf(u1, u1, sq);
            sq = fmaf(u2, u2, sq);
            sq = fmaf(u3, u3, sq);
            ow0[p] = packtrunc(u0, u1);
            ow1[p] = packtrunc(u2, u3);
        }
        *(bf16x8*)&As[s][row][kd * 16] = *(bf16x8*)ow0;
        *(bf16x8*)&As[s][row][kd * 16 + 8] = *(bf16x8*)ow1;
    };

    // prologue: u(0)->As[0], B(0)->Bs[0], prefetch g/c(1)
    loadGC();
    agen(0);
    fillB(0, 0);
    gG += (size_t)NB * 32;
    gC += 512;
    loadGC();

    // B frag base: frag f = wc*8 + nt at f*512 shorts; lane reads lane*8 (contiguous)
    const int boff = (wc * 8) * 512 + lane * 8;

    for (int kc = 0; kc < 32; ++kc) {
        int s = kc & 1;
        __syncthreads();   // As[s]/Bs[s]/g,c(kc+1) ready (all issued last iter)

        if (kc < 31) {
            agen(s ^ 1);            // u(kc+1) -> other A slot (consumes g/c regs first)
            fillB(kc + 1, s ^ 1);   // B(kc+1) DMA, in flight until next barrier
            if (kc < 30) {          // g/c(kc+2) register prefetch
                gG += (size_t)NB * 32;
                gC += 512;
                loadGC();
            }
        }

        // ---- MFMA(kc): wave tile 64 rows x 128 cols ----
        bf16x8 af[4], bfr[8];
#pragma unroll
        for (int mt = 0; mt < 4; mt++)
            af[mt] = *(const bf16x8*)&As[s][wr * 64 + mt * 16 + l15][l4 * 8];
        const unsigned short* bb = Bs[s] + boff;
#pragma unroll
        for (int nt = 0; nt < 8; nt++)
            bfr[nt] = *(const bf16x8*)(bb + nt * 512);
#pragma unroll
        for (int mt = 0; mt < 4; mt++)
#pragma unroll
            for (int nt = 0; nt < 8; nt++)
                acc[mt][nt] = __builtin_amdgcn_mfma_f32_16x16x32_bf16(af[mt], bfr[nt], acc[mt][nt], 0, 0, 0);
    }

    // ---- ||u|| per row: reduce over the 2 kd threads (adjacent lanes) ----
    sq += __shfl_xor(sq, 1, 64);
    if (kd == 0) invnh[row] = 1.0f / (sqrtf(sq) + 1e-8f * nb[bt * 8 + (row & 7)]);
    __syncthreads();

    // ---- epilogue: z = acc*invnh + b2; relu; q-partial over this block's 256 cols ----
    float wqv[8], b2v[8];
#pragma unroll
    for (int nt = 0; nt < 8; nt++) {
        int o = cb * 256 + wc * 128 + nt * 16 + l15;
        wqv[nt] = Wq[o]; b2v[nt] = b2[o];
    }
#pragma unroll
    for (int mt = 0; mt < 4; mt++) {
#pragma unroll
        for (int i = 0; i < 4; i++) {
            int R = wr * 64 + mt * 16 + l4 * 4 + i;
            float inv = invnh[R];
            float qp = 0.f;
#pragma unroll
            for (int nt = 0; nt < 8; nt++) {
                float z = fmaf(acc[mt][nt][i], inv, b2v[nt]);
                z = fmaxf(z, 0.f);
                qp = fmaf(z, wqv[nt], qp);
            }
            qp += __shfl_xor(qp, 1, 64);
            qp += __shfl_xor(qp, 2, 64);
            qp += __shfl_xor(qp, 4, 64);
            qp += __shfl_xor(qp, 8, 64);
            if (l15 == 0) qred[R][wc] = qp;
        }
    }
    __syncthreads();
    if (t < 128) {
        float qv = qred[t][0] + qred[t][1];
        if (cb == 0) qv += bq[0];
        int aa = at * 16 + (t >> 3);
        int bo = bt * 8 + (t & 7);
        atomicAdd(out + (size_t)bo * NA + aa, qv);
    }
}

extern "C" void kernel_launch(void* const* d_in, const int* in_sizes, int n_in,
                              void* d_out, int out_size, void* d_ws, size_t ws_size,
                              hipStream_t stream) {
    const float* states = (const float*)d_in[0];
    const float* W1     = (const float*)d_in[1];
    const float* b1     = (const float*)d_in[2];
    const float* W2     = (const float*)d_in[3];
    const float* b2     = (const float*)d_in[4];
    const float* Wq     = (const float*)d_in[5];
    const float* bq     = (const float*)d_in[6];
    float* out = (float*)d_out;

    char* ws = (char*)d_ws;
    unsigned short* Gt   = (unsigned short*)ws;                              // 8 MB
    unsigned short* W2f  = (unsigned short*)(ws + (8u << 20));               // 1 MB
    unsigned short* caT2 = (unsigned short*)(ws + (9u << 20));               // 128 KB
    float*          nbp  = (float*)(ws + (9u << 20) + (128u << 10));         // 16 KB

    hipMemsetAsync(d_out, 0, (size_t)out_size * sizeof(float), stream);
    knorm<<<NB, 64, 0, stream>>>(states, nbp);
    kprep<<<2304, 256, 0, stream>>>(W1, W2, W2f, caT2);
    kgemm1<<<256, 256, 0, stream>>>(states, W1, b1, nbp, Gt);
    kmain<<<4096, 256, 0, stream>>>(Gt, caT2, W2f, nbp, b2, Wq, bq, out);
}